// Round 9
// baseline (330.863 us; speedup 1.0000x reference)
//
#include <hip/hip_runtime.h>

// ---- problem constants ----
#define D_DIM 1024
#define B_DIM 16
#define T_DIM 2048
#define M_TOT (B_DIM * T_DIM)   // 32768 rows
#define K_DIM 1024
#define LN_EPS 1e-5f
#define CHUNK 16
#define NCH (T_DIM / CHUNK)     // 128 chunks

typedef _Float16 half8 __attribute__((ext_vector_type(8)));
typedef float f32x4 __attribute__((ext_vector_type(4)));

// ---------------- fp32 -> fp16 conversion, 8 elems/thread ----------------
__global__ __launch_bounds__(256) void cvt_f32_f16(const float* __restrict__ in,
                                                   _Float16* __restrict__ out, int n8) {
    int i = blockIdx.x * blockDim.x + threadIdx.x;
    int stride = gridDim.x * blockDim.x;
    for (; i < n8; i += stride) {
        const float4* p = (const float4*)in + 2 * (size_t)i;
        float4 a = p[0], b = p[1];
        half8 h;
        h[0] = (_Float16)a.x; h[1] = (_Float16)a.y; h[2] = (_Float16)a.z; h[3] = (_Float16)a.w;
        h[4] = (_Float16)b.x; h[5] = (_Float16)b.y; h[6] = (_Float16)b.z; h[7] = (_Float16)b.w;
        ((half8*)out)[i] = h;
    }
}

// ---------------- fp32 [1024][1024] -> fp16 transpose (for W_vx^T) ----------------
__global__ __launch_bounds__(256) void transpose_cvt(const float* __restrict__ in,
                                                     _Float16* __restrict__ out) {
    __shared__ _Float16 t[32][33];
    int bx = blockIdx.x * 32, by = blockIdx.y * 32;
    int tx = threadIdx.x, ty = threadIdx.y;   // (32, 8)
#pragma unroll
    for (int j = 0; j < 4; ++j)
        t[ty + 8 * j][tx] = (_Float16)in[(size_t)(by + ty + 8 * j) * 1024 + bx + tx];
    __syncthreads();
#pragma unroll
    for (int j = 0; j < 4; ++j)
        out[(size_t)(bx + ty + 8 * j) * 1024 + by + tx] = t[tx][ty + 8 * j];
}

// ============ packed-B layout ============
// 16B unit index = (nf*32 + kt)*64 + lane, where n = nf*16 + (lane&15),
// k = kt*32 + (lane>>4)*8. A wave's B-frag load (fixed nf, kt) is 64
// consecutive 16B units = 1 KB fully coalesced, and lane l gets exactly the
// 16x16x32 MFMA B fragment (col = lane&15, k-quarter = lane>>4).

// pack W_g (proj cols 0..1023) from W_in rows, with fp32->fp16 convert
__global__ __launch_bounds__(256) void cvt_pack_g(const float* __restrict__ Wg,
                                                  _Float16* __restrict__ pk) {
    int i = blockIdx.x * 256 + threadIdx.x;   // 0..131071 units
    int ll = i & 63, u = i >> 6;
    int kt = u & 31, nf = u >> 5;             // nf 0..63
    int n = nf * 16 + (ll & 15);
    int k = kt * 32 + (ll >> 4) * 8;
    const float4* s = (const float4*)&Wg[(size_t)n * 1024 + k];
    float4 a = s[0], b = s[1];
    half8 h;
    h[0] = (_Float16)a.x; h[1] = (_Float16)a.y; h[2] = (_Float16)a.z; h[3] = (_Float16)a.w;
    h[4] = (_Float16)b.x; h[5] = (_Float16)b.y; h[6] = (_Float16)b.z; h[7] = (_Float16)b.w;
    *(half8*)&pk[(size_t)i * 8] = h;
}

// ---------------- async global->LDS helper ----------------
__device__ __forceinline__ void gl_lds16(const _Float16* g, _Float16* l) {
    __builtin_amdgcn_global_load_lds(
        (const __attribute__((address_space(1))) unsigned int*)g,
        (__attribute__((address_space(3))) unsigned int*)l,
        16, 0, 0);
}

// Stage a full 256x32 fp16 A-tile (16 KiB) = 2 gl_lds / thread.
// Linear LDS dest + inverse-XOR'd global source chunk (both-sides swizzle).
__device__ __forceinline__ void stage32(const _Float16* __restrict__ G,
                                        int row0, int kt,
                                        _Float16* lds0, int wid, int lane) {
#pragma unroll
    for (int call = 0; call < 2; ++call) {
        int c0 = call * 512 + wid * 64;     // wave-uniform chunk base
        int c  = c0 + lane;                 // chunk 0..1023
        int rl = c >> 2;                    // row 0..255 (4 chunks/row)
        int cc = c & 3;
        int src = cc ^ ((rl >> 1) & 3);     // swizzled source 16B-chunk
        gl_lds16(G + (size_t)(row0 + rl) * 1024 + kt + src * 8,
                 lds0 + (size_t)c0 * 8);
    }
}

// Fragment read with matching XOR: conflict-free (0 conflicts measured r7/r8).
__device__ __forceinline__ half8 frag32(const _Float16* base, int row, int kq) {
    int cc = kq ^ ((row >> 1) & 3);
    return *(const half8*)(base + (size_t)row * 32 + cc * 8);
}

// B-frag: one coalesced 16B load per lane from packed layout
__device__ __forceinline__ half8 bload(const _Float16* __restrict__ pb,
                                       int nf, int kt, int lane) {
    return *(const half8*)(pb + (((size_t)nf * 32 + kt) * 64 + lane) * 8);
}

// ========== 256x256 fp16 MFMA GEMM: A via 2-buffer LDS, B direct-to-reg ==========
template <int PB>
__device__ __forceinline__ void gstep(const _Float16* __restrict__ A,
                                      const _Float16* __restrict__ pb,
                                      int m0, int nf0, int t, int nkt,
                                      int wid, int lane, int wr, int wc, int r, int kq,
                                      _Float16 (&As)[2][256][32],
                                      half8 (&bb)[4],
                                      f32x4 (&acc)[8][4]) {
    half8 ra0[4], ra1[4];

    // ---- phase 0: LDS reads mi0-3 ; stage A(t+1) ; barrier ; MFMA acc[0..3] ----
#pragma unroll
    for (int mi = 0; mi < 4; mi++) ra0[mi] = frag32(&As[PB][0][0], wr * 128 + mi * 16 + r, kq);
    if (t + 1 < nkt) stage32(A, m0, (t + 1) << 5, &As[PB ^ 1][0][0], wid, lane);
    __builtin_amdgcn_s_barrier();
    __builtin_amdgcn_s_setprio(1);
#pragma unroll
    for (int mi = 0; mi < 4; mi++)
#pragma unroll
        for (int ni = 0; ni < 4; ni++)
            acc[mi][ni] = __builtin_amdgcn_mfma_f32_16x16x32_f16(ra0[mi], bb[ni], acc[mi][ni], 0, 0, 0);
    __builtin_amdgcn_s_setprio(0);
    __builtin_amdgcn_s_barrier();

    // ---- phase 1: LDS reads mi4-7 ; vmcnt(0) [only A(t+1) outstanding] ;
    //      barrier ; MFMA acc[4..7] ; then issue B(t+1) into bb (WAR-safe) ----
#pragma unroll
    for (int mi = 0; mi < 4; mi++) ra1[mi] = frag32(&As[PB][0][0], wr * 128 + 64 + mi * 16 + r, kq);
    if (t + 1 < nkt) asm volatile("s_waitcnt vmcnt(0)" ::: "memory");   // A(t+1) landed
    __builtin_amdgcn_s_barrier();                                        // all waves: visible
    __builtin_amdgcn_s_setprio(1);
#pragma unroll
    for (int mi = 0; mi < 4; mi++)
#pragma unroll
        for (int ni = 0; ni < 4; ni++)
            acc[4 + mi][ni] = __builtin_amdgcn_mfma_f32_16x16x32_f16(ra1[mi], bb[ni], acc[4 + mi][ni], 0, 0, 0);
    __builtin_amdgcn_s_setprio(0);
    if (t + 1 < nkt) {
#pragma unroll
        for (int ni = 0; ni < 4; ni++) bb[ni] = bload(pb, nf0 + ni, t + 1, lane);
    }
    __builtin_amdgcn_s_barrier();
}

// out0 = sigmoid(proj[:, :1024]), out1 = proj[:, 1024:]  (both fp16)
__global__ __launch_bounds__(512, 2) void gemm256(const _Float16* __restrict__ A,
                                                  const _Float16* __restrict__ pb,
                                                  _Float16* __restrict__ out0,
                                                  _Float16* __restrict__ out1) {
    __shared__ _Float16 As[2][256][32];   // 32 KiB

    int bid = blockIdx.x;
    // 2-D XCD supertile: each XCD owns 16 mt x 8 nt
    int xcd = bid & 7;
    int mt = xcd * 16 + ((bid >> 3) & 15);
    int nt = bid >> 7;
    int m0 = mt * 256;

    int tid = threadIdx.x, wid = tid >> 6, lane = tid & 63;
    int wr = wid >> 2, wc = wid & 3;         // 2 x 4 wave grid, per-wave 128x64
    int r = lane & 15, kq = lane >> 4;
    int nf0 = nt * 16 + wc * 4;              // packed-B col-frag base for this wave

    f32x4 acc[8][4];
#pragma unroll
    for (int i = 0; i < 8; i++)
#pragma unroll
        for (int j = 0; j < 4; j++) acc[i][j] = (f32x4)0.f;

    half8 bb[4];
    const int nkt = K_DIM >> 5;              // 32 K-tiles of BK=32

    // ---- prologue: stage A0 ; load B0 ; wait A0 (leave B's 4) ; barrier ----
    stage32(A, m0, 0, &As[0][0][0], wid, lane);
#pragma unroll
    for (int ni = 0; ni < 4; ni++) bb[ni] = bload(pb, nf0 + ni, 0, lane);
    asm volatile("s_waitcnt vmcnt(4)" ::: "memory");
    __builtin_amdgcn_s_barrier();

    for (int t0 = 0; t0 < nkt; t0 += 2) {
        gstep<0>(A, pb, m0, nf0, t0,     nkt, wid, lane, wr, wc, r, kq, As, bb, acc);
        gstep<1>(A, pb, m0, nf0, t0 + 1, nkt, wid, lane, wr, wc, r, kq, As, bb, acc);
    }

    // ---- epilogue: C/D layout col = lane&15, row = (lane>>4)*4 + q ----
    int rr = kq * 4;
#pragma unroll
    for (int mi = 0; mi < 8; mi++) {
        int mbase = m0 + wr * 128 + mi * 16 + rr;
#pragma unroll
        for (int ni = 0; ni < 4; ni++) {
            int n = nt * 256 + wc * 64 + ni * 16 + r;
#pragma unroll
            for (int q = 0; q < 4; q++) {
                float v = acc[mi][ni][q];
                size_t m = (size_t)(mbase + q);
                if (n < D_DIM)
                    out0[m * D_DIM + n] = (_Float16)(1.f / (1.f + __expf(-v)));
                else
                    out1[m * D_DIM + (n - D_DIM)] = (_Float16)v;
            }
        }
    }
}

// ========== split-K W_comb GEMM (128x128 tile, r2-validated structure) ==========
// part[sl][e][k] = sum_{kk in slice sl} Wst[e][kk] * WvxT[k][kk]   (fp32 partials)
__global__ __launch_bounds__(256) void wcomb_splitk(const _Float16* __restrict__ A,
                                                    const _Float16* __restrict__ Bm,
                                                    float* __restrict__ part) {
    __shared__ _Float16 As[128 * 32];
    __shared__ _Float16 Bs[128 * 32];
    int bid = blockIdx.x;                 // mt + 8*nt + 64*slice
    int mt = bid & 7, nt = (bid >> 3) & 7, sl = bid >> 6;
    int m0 = mt * 128, n0 = nt * 128, kbeg = sl * 256;
    int tid = threadIdx.x, wid = tid >> 6, lane = tid & 63;
    int wr = wid >> 1, wc = wid & 1;

    f32x4 acc[4][4];
#pragma unroll
    for (int i = 0; i < 4; i++)
#pragma unroll
        for (int j = 0; j < 4; j++) acc[i][j] = (f32x4)0.f;

    int r = lane & 15, kq = lane >> 4;

    for (int kt = kbeg; kt < kbeg + 256; kt += 32) {
        __syncthreads();
#pragma unroll
        for (int j = 0; j < 2; ++j) {
            int f = j * 256 + tid;
            int row = f >> 2, kc = f & 3;
            gl_lds16(A + (size_t)(m0 + row) * 1024 + kt + kc * 8, As + (size_t)(j * 256 + wid * 64) * 8);
            gl_lds16(Bm + (size_t)(n0 + row) * 1024 + kt + kc * 8, Bs + (size_t)(j * 256 + wid * 64) * 8);
        }
        __syncthreads();
        half8 af[4], bf[4];
#pragma unroll
        for (int mi = 0; mi < 4; mi++) af[mi] = *(const half8*)&As[(wr * 64 + mi * 16 + r) * 32 + kq * 8];
#pragma unroll
        for (int ni = 0; ni < 4; ni++) bf[ni] = *(const half8*)&Bs[(wc * 64 + ni * 16 + r) * 32 + kq * 8];
#pragma unroll
        for (int mi = 0; mi < 4; mi++)
#pragma unroll
            for (int ni = 0; ni < 4; ni++)
                acc[mi][ni] = __builtin_amdgcn_mfma_f32_16x16x32_f16(af[mi], bf[ni], acc[mi][ni], 0, 0, 0);
    }

    int rr = kq * 4;
    float* pbp = part + (size_t)sl * 1048576;
#pragma unroll
    for (int mi = 0; mi < 4; mi++) {
        int mbase = m0 + wr * 64 + mi * 16 + rr;
#pragma unroll
        for (int ni = 0; ni < 4; ni++) {
            int n = n0 + wc * 64 + ni * 16 + r;
#pragma unroll
            for (int q = 0; q < 4; q++)
                pbp[(size_t)(mbase + q) * 1024 + n] = acc[mi][ni][q];
        }
    }
}

// combine 4 split-K slices and write DIRECTLY in packed-B layout (cols 1024..2047)
__global__ __launch_bounds__(256) void wcomb_combine_pack(const float* __restrict__ part,
                                                          _Float16* __restrict__ pk) {
    int i = blockIdx.x * 256 + threadIdx.x;   // 0..131071 units
    int ll = i & 63, u = i >> 6;
    int kt = u & 31, nf = u >> 5;             // local nf 0..63
    int e = nf * 16 + (ll & 15);              // W_comb row = proj col - 1024
    int k = kt * 32 + (ll >> 4) * 8;
    size_t o = (size_t)e * 1024 + k;
    float s[8];
#pragma unroll
    for (int j = 0; j < 8; ++j) s[j] = 0.f;
#pragma unroll
    for (int sl = 0; sl < 4; ++sl) {
        const float4* p = (const float4*)&part[(size_t)sl * 1048576 + o];
        float4 a = p[0], b = p[1];
        s[0] += a.x; s[1] += a.y; s[2] += a.z; s[3] += a.w;
        s[4] += b.x; s[5] += b.y; s[6] += b.z; s[7] += b.w;
    }
    half8 h;
#pragma unroll
    for (int j = 0; j < 8; ++j) h[j] = (_Float16)s[j];
    *(half8*)&pk[1048576 + (size_t)i * 8] = h;   // second half of packed array
}

// ---------------- chunked affine scan, pass 1 (CHUNK=16) ----------------
__global__ __launch_bounds__(256) void scan_pass1(const _Float16* __restrict__ u,
                                                  const _Float16* __restrict__ cd,
                                                  float* __restrict__ Ac, float* __restrict__ Bc) {
    int idx = blockIdx.x * 256 + threadIdx.x;   // (b*NCH + ch)*128 + dg
    int dg = idx & 127, bc = idx >> 7;
    int b = bc >> 7, ch = bc & (NCH - 1);
    int d0 = dg * 8;
    size_t base = ((size_t)b * T_DIM + (size_t)ch * CHUNK) * D_DIM + d0;
    float Aa[8], Bb[8];
#pragma unroll
    for (int j = 0; j < 8; ++j) { Aa[j] = 1.f; Bb[j] = 0.f; }
#pragma unroll
    for (int t = 0; t < CHUNK; ++t) {
        half8 u8 = *(const half8*)&u[base + (size_t)t * D_DIM];
        half8 c8 = *(const half8*)&cd[base + (size_t)t * D_DIM];
#pragma unroll
        for (int j = 0; j < 8; ++j) {
            float ut = (float)u8[j], ct = (float)c8[j];
            Aa[j] *= ut;
            Bb[j] = fmaf(ut, Bb[j], (1.f - ut) * ct);
        }
    }
    size_t o = (size_t)bc * D_DIM + d0;
    *(float4*)&Ac[o]     = *(float4*)&Aa[0];
    *(float4*)&Ac[o + 4] = *(float4*)&Aa[4];
    *(float4*)&Bc[o]     = *(float4*)&Bb[0];
    *(float4*)&Bc[o + 4] = *(float4*)&Bb[4];
}

// pass 2: sequential over chunks; AcH0 doubles as h0 output (read-before-write)
__global__ __launch_bounds__(256) void scan_pass2(float* __restrict__ AcH0,
                                                  const float* __restrict__ Bc) {
    int idx = blockIdx.x * 256 + threadIdx.x;   // b*D + d, 16384 total
    int b = idx >> 10, d = idx & (D_DIM - 1);
    float h = 0.f;
#pragma unroll 8
    for (int ch = 0; ch < NCH; ++ch) {
        size_t k = ((size_t)(b * NCH + ch) << 10) + d;
        float a = AcH0[k];
        float bv = Bc[k];
        AcH0[k] = h;
        h = fmaf(a, h, bv);
    }
}

// ---------------- fused scan pass 3 + LayerNorm (1 wave, 16 dims/lane) ----------------
__global__ __launch_bounds__(64) void scan_ln(const _Float16* __restrict__ u,
                                              const _Float16* __restrict__ cd,
                                              const float* __restrict__ h0,
                                              const float* __restrict__ gamma,
                                              const float* __restrict__ beta,
                                              float* __restrict__ outp) {
    int bc = blockIdx.x;                // b*NCH + ch
    int b = bc >> 7, ch = bc & (NCH - 1);
    int lane = threadIdx.x;             // 0..63
    int d0 = lane * 16;
    size_t base = ((size_t)b * T_DIM + (size_t)ch * CHUNK) * D_DIM + d0;

    float g[16], be[16], h[16];
#pragma unroll
    for (int j = 0; j < 16; j += 4) {
        *(float4*)&g[j]  = *(const float4*)&gamma[d0 + j];
        *(float4*)&be[j] = *(const float4*)&beta[d0 + j];
    }
    size_t o = (size_t)bc * D_DIM + d0;
#pragma unroll
    for (int j = 0; j < 16; j += 4) *(float4*)&h[j] = *(const float4*)&h0[o + j];

    for (int t = 0; t < CHUNK; ++t) {
        size_t row = base + (size_t)t * D_DIM;
        half8 ua = *(const half8*)&u[row];
        half8 ub = *(const half8*)&u[row + 8];
        half8 ca = *(const half8*)&cd[row];
        half8 cb = *(const half8*)&cd[row + 8];
        float s = 0.f, q = 0.f;
#pragma unroll
        for (int j = 0; j < 8; ++j) {
            float ut = (float)ua[j], ct = (float)ca[j];
            h[j] = fmaf(ut, h[j] - ct, ct);
            s += h[j]; q += h[j] * h[j];
        }
#pragma unroll
        for (int j = 0; j < 8; ++j) {
            float ut = (float)ub[j], ct = (float)cb[j];
            h[8 + j] = fmaf(ut, h[8 + j] - ct, ct);
            s += h[8 + j]; q += h[8 + j] * h[8 + j];
        }
#pragma unroll
        for (int off = 32; off > 0; off >>= 1) {
            s += __shfl_xor(s, off);
            q += __shfl_xor(q, off);
        }
        float mu = s * (1.f / D_DIM);
        float var = q * (1.f / D_DIM) - mu * mu;
        float rs = rsqrtf(var + LN_EPS);
        float o16[16];
#pragma unroll
        for (int j = 0; j < 16; ++j) o16[j] = (h[j] - mu) * rs * g[j] + be[j];
#pragma unroll
        for (int j = 0; j < 16; j += 4) *(float4*)&outp[row + j] = *(float4*)&o16[j];
    }
}

extern "C" void kernel_launch(void* const* d_in, const int* in_sizes, int n_in,
                              void* d_out, int out_size, void* d_ws, size_t ws_size,
                              hipStream_t stream) {
    const float* x       = (const float*)d_in[0];
    const float* W_in    = (const float*)d_in[1];
    const float* W_state = (const float*)d_in[2];
    const float* gamma   = (const float*)d_in[3];
    const float* beta    = (const float*)d_in[4];
    float* out = (float*)d_out;

    char* w = (char*)d_ws;
    size_t off = 0;
    auto carve = [&](size_t bytes) {
        void* p = w + off;
        off += (bytes + 255) & ~(size_t)255;
        return p;
    };
    _Float16* xh  = (_Float16*)carve((size_t)M_TOT * K_DIM * 2);            // 64 MiB
    _Float16* pk  = (_Float16*)carve((size_t)2 * D_DIM * K_DIM * 2);        // 4 MiB packed B
    _Float16* uarr = (_Float16*)carve((size_t)M_TOT * D_DIM * 2);           // 64 MiB
    _Float16* cand = (_Float16*)carve((size_t)M_TOT * D_DIM * 2);           // 64 MiB
    char* scratch  = (char*)carve((size_t)16 * 1024 * 1024);                // 16 MiB shared region
    _Float16* wvxT = (_Float16*)scratch;                                    // 2 MiB (early)
    _Float16* wst  = (_Float16*)(scratch + 2 * 1024 * 1024);                // 2 MiB (early)
    float* Ac = (float*)scratch;                                            // 8 MiB (late, also h0)
    float* Bc = (float*)(scratch + 8 * 1024 * 1024);                        // 8 MiB (late)
    float* wpart = (float*)cand;   // 16 MiB fp32 partials; cand dead until main GEMM

    // 1. casts / packing
    cvt_f32_f16<<<2048, 256, 0, stream>>>(x, xh, M_TOT * K_DIM / 8);
    cvt_pack_g<<<512, 256, 0, stream>>>(W_in, pk);                          // W_g -> packed[0:]
    transpose_cvt<<<dim3(32, 32), dim3(32, 8), 0, stream>>>(W_in + (size_t)D_DIM * K_DIM, wvxT);
    cvt_f32_f16<<<512, 256, 0, stream>>>(W_state, wst, D_DIM * K_DIM / 8);

    // 2. W_comb = W_state @ W_vx -> packed[1M:]  (split-K x4 + packing combine)
    wcomb_splitk<<<256, 256, 0, stream>>>(wst, wvxT, wpart);
    wcomb_combine_pack<<<512, 256, 0, stream>>>(wpart, pk);

    // 3. fused projection: [u | cand] = x @ Wall^T  (sigmoid on u half)
    gemm256<<<1024, 512, 0, stream>>>(xh, pk, uarr, cand);

    // 4. chunked affine scan + fused LN
    scan_pass1<<<(B_DIM * NCH * 128) / 256, 256, 0, stream>>>(uarr, cand, Ac, Bc);
    scan_pass2<<<(B_DIM * D_DIM) / 256, 256, 0, stream>>>(Ac, Bc);
    scan_ln<<<B_DIM * NCH, 64, 0, stream>>>(uarr, cand, Ac, gamma, beta, out);
}

// Round 13
// 308.164 us; speedup vs baseline: 1.0737x; 1.0737x over previous
//
#include <hip/hip_runtime.h>

// ---- problem constants ----
#define D_DIM 1024
#define B_DIM 16
#define T_DIM 2048
#define M_TOT (B_DIM * T_DIM)   // 32768 rows
#define K_DIM 1024
#define LN_EPS 1e-5f
#define CHUNK 16
#define NCH (T_DIM / CHUNK)     // 128 chunks

typedef _Float16 half8 __attribute__((ext_vector_type(8)));
typedef _Float16 half4v __attribute__((ext_vector_type(4)));
typedef float f32x4 __attribute__((ext_vector_type(4)));

// ---------------- fp32 -> fp16 conversion, 8 elems/thread ----------------
__global__ __launch_bounds__(256) void cvt_f32_f16(const float* __restrict__ in,
                                                   _Float16* __restrict__ out, int n8) {
    int i = blockIdx.x * blockDim.x + threadIdx.x;
    int stride = gridDim.x * blockDim.x;
    for (; i < n8; i += stride) {
        const float4* p = (const float4*)in + 2 * (size_t)i;
        float4 a = p[0], b = p[1];
        half8 h;
        h[0] = (_Float16)a.x; h[1] = (_Float16)a.y; h[2] = (_Float16)a.z; h[3] = (_Float16)a.w;
        h[4] = (_Float16)b.x; h[5] = (_Float16)b.y; h[6] = (_Float16)b.z; h[7] = (_Float16)b.w;
        ((half8*)out)[i] = h;
    }
}

// ---------------- fp32 [1024][1024] -> fp16 transpose (for W_vx^T) ----------------
__global__ __launch_bounds__(256) void transpose_cvt(const float* __restrict__ in,
                                                     _Float16* __restrict__ out) {
    __shared__ _Float16 t[32][33];
    int bx = blockIdx.x * 32, by = blockIdx.y * 32;
    int tx = threadIdx.x, ty = threadIdx.y;   // (32, 8)
#pragma unroll
    for (int j = 0; j < 4; ++j)
        t[ty + 8 * j][tx] = (_Float16)in[(size_t)(by + ty + 8 * j) * 1024 + bx + tx];
    __syncthreads();
#pragma unroll
    for (int j = 0; j < 4; ++j)
        out[(size_t)(bx + ty + 8 * j) * 1024 + by + tx] = t[tx][ty + 8 * j];
}

// ---------------- async global->LDS helper ----------------
__device__ __forceinline__ void gl_lds16(const _Float16* g, _Float16* l) {
    __builtin_amdgcn_global_load_lds(
        (const __attribute__((address_space(1))) unsigned int*)g,
        (__attribute__((address_space(3))) unsigned int*)l,
        16, 0, 0);
}

// ====== 128x256 fp16 MFMA GEMM, 4 waves, 2 blocks/CU (inter-block overlap) ======
// RACE FIX (r10->r11): per-tile order restored to the r7-proven
//   vmcnt -> barrier -> ds_reads -> stage -> MFMA  sequence.
// 3-buffer LDS; stage tile t+2 after tile t's start barrier; own-wave vmcnt(6)
// at tile top lands S_t exactly (S_{t+1} stays in flight); ~1.5-tile slack.

// Stage 128x32 A-tile (8 KiB, 512 chunks) = 2 gl_lds / thread.
__device__ __forceinline__ void stageA32(const _Float16* __restrict__ G,
                                         int row0, int kt,
                                         _Float16* lds0, int wid, int lane) {
#pragma unroll
    for (int call = 0; call < 2; ++call) {
        int c0 = call * 256 + wid * 64;
        int c  = c0 + lane;                 // chunk 0..511
        int rl = c >> 2;                    // row 0..127
        int cc = c & 3;
        int src = cc ^ ((rl >> 1) & 3);     // both-sides swizzle (0 conflicts r7/r8)
        gl_lds16(G + (size_t)(row0 + rl) * 1024 + kt + src * 8,
                 lds0 + (size_t)c0 * 8);
    }
}

// Stage 256x32 B-tile (16 KiB, 1024 chunks) = 4 gl_lds / thread.
__device__ __forceinline__ void stageB32(const _Float16* __restrict__ G,
                                         int row0, int kt,
                                         _Float16* lds0, int wid, int lane) {
#pragma unroll
    for (int call = 0; call < 4; ++call) {
        int c0 = call * 256 + wid * 64;
        int c  = c0 + lane;                 // chunk 0..1023
        int rl = c >> 2;                    // row 0..255
        int cc = c & 3;
        int src = cc ^ ((rl >> 1) & 3);
        gl_lds16(G + (size_t)(row0 + rl) * 1024 + kt + src * 8,
                 lds0 + (size_t)c0 * 8);
    }
}

// Fragment read with matching XOR (conflict-free, measured r7/r8).
__device__ __forceinline__ half8 frag32(const _Float16* base, int row, int kq) {
    int cc = kq ^ ((row >> 1) & 3);
    return *(const half8*)(base + (size_t)row * 32 + cc * 8);
}

template <int TB>
__device__ __forceinline__ void gstep(const _Float16* __restrict__ A,
                                      const _Float16* __restrict__ W,
                                      int m0, int nrow0, int t, int nkt,
                                      int wid, int lane, int wc, int r, int kq,
                                      _Float16 (&As)[3][128][32],
                                      _Float16 (&Bs)[3][256][32],
                                      f32x4 (&acc)[8][4]) {
    constexpr int NB = (TB + 2) % 3;
    half8 rb[4], ra0[4], ra1[4];

    // ---- tile top: own vmcnt lands S_t ; barrier makes ALL waves' S_t visible ----
    if (t + 1 < nkt) asm volatile("s_waitcnt vmcnt(6)" ::: "memory");
    else             asm volatile("s_waitcnt vmcnt(0)" ::: "memory");
    __builtin_amdgcn_s_barrier();
    __builtin_amdgcn_sched_barrier(0);       // pin reads BELOW the barrier (rule #18)

    // ---- ph0: ds rb+ra0 ; stage S_{t+2} ; MFMA 0..3 ----
#pragma unroll
    for (int ni = 0; ni < 4; ni++) rb[ni]  = frag32(&Bs[TB][0][0], wc * 64 + ni * 16 + r, kq);
#pragma unroll
    for (int mi = 0; mi < 4; mi++) ra0[mi] = frag32(&As[TB][0][0], mi * 16 + r, kq);
    if (t + 2 < nkt) {
        int kt2 = (t + 2) << 5;
        stageA32(A, m0,    kt2, &As[NB][0][0], wid, lane);
        stageB32(W, nrow0, kt2, &Bs[NB][0][0], wid, lane);
    }
    __builtin_amdgcn_s_setprio(1);
#pragma unroll
    for (int mi = 0; mi < 4; mi++)
#pragma unroll
        for (int ni = 0; ni < 4; ni++)
            acc[mi][ni] = __builtin_amdgcn_mfma_f32_16x16x32_f16(ra0[mi], rb[ni], acc[mi][ni], 0, 0, 0);
    __builtin_amdgcn_s_setprio(0);

    // ---- ph1: ds ra1 ; MFMA 4..7 ; end barrier (reads consumed -> restage safe) ----
#pragma unroll
    for (int mi = 0; mi < 4; mi++) ra1[mi] = frag32(&As[TB][0][0], 64 + mi * 16 + r, kq);
    __builtin_amdgcn_s_setprio(1);
#pragma unroll
    for (int mi = 0; mi < 4; mi++)
#pragma unroll
        for (int ni = 0; ni < 4; ni++)
            acc[4 + mi][ni] = __builtin_amdgcn_mfma_f32_16x16x32_f16(ra1[mi], rb[ni], acc[4 + mi][ni], 0, 0, 0);
    __builtin_amdgcn_s_setprio(0);
    __builtin_amdgcn_s_barrier();
}

// W rows 0..1023 = gate weights, 1024..2047 = W_comb. nt<4 -> sigmoid -> out0.
__global__ __launch_bounds__(256, 2) void gemm256(const _Float16* __restrict__ A,
                                                  const _Float16* __restrict__ W,
                                                  _Float16* __restrict__ out0,
                                                  _Float16* __restrict__ out1) {
    __shared__ _Float16 As[3][128][32];   // 24 KiB
    __shared__ _Float16 Bs[3][256][32];   // 48 KiB  (72 KiB total -> 2 blocks/CU)

    int bid = blockIdx.x;                 // 2048 blocks
    int xcd = bid & 7, lin = bid >> 3;    // 256 blocks/XCD
    int mt = xcd * 32 + (lin >> 3);       // 32 mt x 8 nt per XCD (A panel reused 8x)
    int nt = lin & 7;
    int m0 = mt * 128, nrow0 = nt * 256;

    int tid = threadIdx.x, wid = tid >> 6, lane = tid & 63;
    int wc = wid;                          // 1x4 wave grid: wave owns 64 cols
    int r = lane & 15, kq = lane >> 4;

    f32x4 acc[8][4];
#pragma unroll
    for (int i = 0; i < 8; i++)
#pragma unroll
        for (int j = 0; j < 4; j++) acc[i][j] = (f32x4)0.f;

    const int nkt = K_DIM >> 5;            // 32 K-tiles

    // ---- prologue: stage tiles 0,1 (12 loads/thread); loop-top vmcnt handles wait ----
    stageA32(A, m0,    0,  &As[0][0][0], wid, lane);
    stageB32(W, nrow0, 0,  &Bs[0][0][0], wid, lane);
    stageA32(A, m0,    32, &As[1][0][0], wid, lane);
    stageB32(W, nrow0, 32, &Bs[1][0][0], wid, lane);

    for (int t0 = 0; t0 < nkt; t0 += 3) {
        gstep<0>(A, W, m0, nrow0, t0, nkt, wid, lane, wc, r, kq, As, Bs, acc);
        if (t0 + 1 < nkt)
            gstep<1>(A, W, m0, nrow0, t0 + 1, nkt, wid, lane, wc, r, kq, As, Bs, acc);
        if (t0 + 2 < nkt)
            gstep<2>(A, W, m0, nrow0, t0 + 2, nkt, wid, lane, wc, r, kq, As, Bs, acc);
    }

    // ---- epilogue: C/D layout col = lane&15, row = (lane>>4)*4 + q ----
    bool isGate = (nt < 4);
    _Float16* dst = isGate ? out0 : out1;
    int cb = (nt & 3) * 256 + wc * 64;
    int rr = kq * 4;
#pragma unroll
    for (int mi = 0; mi < 8; mi++) {
        int mbase = m0 + mi * 16 + rr;
#pragma unroll
        for (int ni = 0; ni < 4; ni++) {
            int n = cb + ni * 16 + r;
#pragma unroll
            for (int q = 0; q < 4; q++) {
                float v = acc[mi][ni][q];
                if (isGate) v = 1.f / (1.f + __expf(-v));
                dst[(size_t)(mbase + q) * D_DIM + n] = (_Float16)v;
            }
        }
    }
}

// ========== split-K W_comb GEMM (128x128 tile, r2-validated structure) ==========
__global__ __launch_bounds__(256) void wcomb_splitk(const _Float16* __restrict__ A,
                                                    const _Float16* __restrict__ Bm,
                                                    float* __restrict__ part) {
    __shared__ _Float16 As[128 * 32];
    __shared__ _Float16 Bs[128 * 32];
    int bid = blockIdx.x;                 // mt + 8*nt + 64*slice
    int mt = bid & 7, nt = (bid >> 3) & 7, sl = bid >> 6;
    int m0 = mt * 128, n0 = nt * 128, kbeg = sl * 256;
    int tid = threadIdx.x, wid = tid >> 6, lane = tid & 63;
    int wr = wid >> 1, wc = wid & 1;

    f32x4 acc[4][4];
#pragma unroll
    for (int i = 0; i < 4; i++)
#pragma unroll
        for (int j = 0; j < 4; j++) acc[i][j] = (f32x4)0.f;

    int r = lane & 15, kq = lane >> 4;

    for (int kt = kbeg; kt < kbeg + 256; kt += 32) {
        __syncthreads();
#pragma unroll
        for (int j = 0; j < 2; ++j) {
            int f = j * 256 + tid;
            int row = f >> 2, kc = f & 3;
            gl_lds16(A + (size_t)(m0 + row) * 1024 + kt + kc * 8, As + (size_t)(j * 256 + wid * 64) * 8);
            gl_lds16(Bm + (size_t)(n0 + row) * 1024 + kt + kc * 8, Bs + (size_t)(j * 256 + wid * 64) * 8);
        }
        __syncthreads();
        half8 af[4], bf[4];
#pragma unroll
        for (int mi = 0; mi < 4; mi++) af[mi] = *(const half8*)&As[(wr * 64 + mi * 16 + r) * 32 + kq * 8];
#pragma unroll
        for (int ni = 0; ni < 4; ni++) bf[ni] = *(const half8*)&Bs[(wc * 64 + ni * 16 + r) * 32 + kq * 8];
#pragma unroll
        for (int mi = 0; mi < 4; mi++)
#pragma unroll
            for (int ni = 0; ni < 4; ni++)
                acc[mi][ni] = __builtin_amdgcn_mfma_f32_16x16x32_f16(af[mi], bf[ni], acc[mi][ni], 0, 0, 0);
    }

    int rr = kq * 4;
    float* pbp = part + (size_t)sl * 1048576;
#pragma unroll
    for (int mi = 0; mi < 4; mi++) {
        int mbase = m0 + wr * 64 + mi * 16 + rr;
#pragma unroll
        for (int ni = 0; ni < 4; ni++) {
            int n = n0 + wc * 64 + ni * 16 + r;
#pragma unroll
            for (int q = 0; q < 4; q++)
                pbp[(size_t)(mbase + q) * 1024 + n] = acc[mi][ni][q];
        }
    }
}

// combine 4 split-K slices -> W rows 1024..2047 (row-major fp16)
__global__ __launch_bounds__(256) void wcomb_combine(const float* __restrict__ part,
                                                     _Float16* __restrict__ out) {
    int i = blockIdx.x * 256 + threadIdx.x;   // 0..262143 (float4 units)
    float4 s0 = ((const float4*)part)[i];
    float4 s1 = ((const float4*)(part + 1048576))[i];
    float4 s2 = ((const float4*)(part + 2097152))[i];
    float4 s3 = ((const float4*)(part + 3145728))[i];
    half4v o;
    o[0] = (_Float16)(s0.x + s1.x + s2.x + s3.x);
    o[1] = (_Float16)(s0.y + s1.y + s2.y + s3.y);
    o[2] = (_Float16)(s0.z + s1.z + s2.z + s3.z);
    o[3] = (_Float16)(s0.w + s1.w + s2.w + s3.w);
    ((half4v*)out)[i] = o;
}

// ---------------- chunked affine scan, pass 1 (CHUNK=16) ----------------
__global__ __launch_bounds__(256) void scan_pass1(const _Float16* __restrict__ u,
                                                  const _Float16* __restrict__ cd,
                                                  float* __restrict__ Ac, float* __restrict__ Bc) {
    int idx = blockIdx.x * 256 + threadIdx.x;   // (b*NCH + ch)*128 + dg
    int dg = idx & 127, bc = idx >> 7;
    int b = bc >> 7, ch = bc & (NCH - 1);
    int d0 = dg * 8;
    size_t base = ((size_t)b * T_DIM + (size_t)ch * CHUNK) * D_DIM + d0;
    float Aa[8], Bb[8];
#pragma unroll
    for (int j = 0; j < 8; ++j) { Aa[j] = 1.f; Bb[j] = 0.f; }
#pragma unroll
    for (int t = 0; t < CHUNK; ++t) {
        half8 u8 = *(const half8*)&u[base + (size_t)t * D_DIM];
        half8 c8 = *(const half8*)&cd[base + (size_t)t * D_DIM];
#pragma unroll
        for (int j = 0; j < 8; ++j) {
            float ut = (float)u8[j], ct = (float)c8[j];
            Aa[j] *= ut;
            Bb[j] = fmaf(ut, Bb[j], (1.f - ut) * ct);
        }
    }
    size_t o = (size_t)bc * D_DIM + d0;
    *(float4*)&Ac[o]     = *(float4*)&Aa[0];
    *(float4*)&Ac[o + 4] = *(float4*)&Aa[4];
    *(float4*)&Bc[o]     = *(float4*)&Bb[0];
    *(float4*)&Bc[o + 4] = *(float4*)&Bb[4];
}

// pass 2: sequential over chunks; AcH0 doubles as h0 output (read-before-write)
__global__ __launch_bounds__(256) void scan_pass2(float* __restrict__ AcH0,
                                                  const float* __restrict__ Bc) {
    int idx = blockIdx.x * 256 + threadIdx.x;   // b*D + d, 16384 total
    int b = idx >> 10, d = idx & (D_DIM - 1);
    float h = 0.f;
#pragma unroll 8
    for (int ch = 0; ch < NCH; ++ch) {
        size_t k = ((size_t)(b * NCH + ch) << 10) + d;
        float a = AcH0[k];
        float bv = Bc[k];
        AcH0[k] = h;
        h = fmaf(a, h, bv);
    }
}

// ---------------- fused scan pass 3 + LayerNorm (1 wave, 16 dims/lane) ----------------
__global__ __launch_bounds__(64) void scan_ln(const _Float16* __restrict__ u,
                                              const _Float16* __restrict__ cd,
                                              const float* __restrict__ h0,
                                              const float* __restrict__ gamma,
                                              const float* __restrict__ beta,
                                              float* __restrict__ outp) {
    int bc = blockIdx.x;                // b*NCH + ch
    int b = bc >> 7, ch = bc & (NCH - 1);
    int lane = threadIdx.x;             // 0..63
    int d0 = lane * 16;
    size_t base = ((size_t)b * T_DIM + (size_t)ch * CHUNK) * D_DIM + d0;

    float g[16], be[16], h[16];
#pragma unroll
    for (int j = 0; j < 16; j += 4) {
        *(float4*)&g[j]  = *(const float4*)&gamma[d0 + j];
        *(float4*)&be[j] = *(const float4*)&beta[d0 + j];
    }
    size_t o = (size_t)bc * D_DIM + d0;
#pragma unroll
    for (int j = 0; j < 16; j += 4) *(float4*)&h[j] = *(const float4*)&h0[o + j];

    for (int t = 0; t < CHUNK; ++t) {
        size_t row = base + (size_t)t * D_DIM;
        half8 ua = *(const half8*)&u[row];
        half8 ub = *(const half8*)&u[row + 8];
        half8 ca = *(const half8*)&cd[row];
        half8 cb = *(const half8*)&cd[row + 8];
        float s = 0.f, q = 0.f;
#pragma unroll
        for (int j = 0; j < 8; ++j) {
            float ut = (float)ua[j], ct = (float)ca[j];
            h[j] = fmaf(ut, h[j] - ct, ct);
            s += h[j]; q += h[j] * h[j];
        }
#pragma unroll
        for (int j = 0; j < 8; ++j) {
            float ut = (float)ub[j], ct = (float)cb[j];
            h[8 + j] = fmaf(ut, h[8 + j] - ct, ct);
            s += h[8 + j]; q += h[8 + j] * h[8 + j];
        }
#pragma unroll
        for (int off = 32; off > 0; off >>= 1) {
            s += __shfl_xor(s, off);
            q += __shfl_xor(q, off);
        }
        float mu = s * (1.f / D_DIM);
        float var = q * (1.f / D_DIM) - mu * mu;
        float rs = rsqrtf(var + LN_EPS);
        float o16[16];
#pragma unroll
        for (int j = 0; j < 16; ++j) o16[j] = (h[j] - mu) * rs * g[j] + be[j];
#pragma unroll
        for (int j = 0; j < 16; j += 4) *(float4*)&outp[row + j] = *(float4*)&o16[j];
    }
}

extern "C" void kernel_launch(void* const* d_in, const int* in_sizes, int n_in,
                              void* d_out, int out_size, void* d_ws, size_t ws_size,
                              hipStream_t stream) {
    const float* x       = (const float*)d_in[0];
    const float* W_in    = (const float*)d_in[1];
    const float* W_state = (const float*)d_in[2];
    const float* gamma   = (const float*)d_in[3];
    const float* beta    = (const float*)d_in[4];
    float* out = (float*)d_out;

    char* w = (char*)d_ws;
    size_t off = 0;
    auto carve = [&](size_t bytes) {
        void* p = w + off;
        off += (bytes + 255) & ~(size_t)255;
        return p;
    };
    _Float16* xh   = (_Float16*)carve((size_t)M_TOT * K_DIM * 2);           // 64 MiB
    _Float16* Wall = (_Float16*)carve((size_t)2 * D_DIM * K_DIM * 2);       // 4 MiB (W_g ; W_comb)
    _Float16* uarr = (_Float16*)carve((size_t)M_TOT * D_DIM * 2);           // 64 MiB
    _Float16* cand = (_Float16*)carve((size_t)M_TOT * D_DIM * 2);           // 64 MiB
    char* scratch  = (char*)carve((size_t)16 * 1024 * 1024);                // 16 MiB shared region
    _Float16* wvxT = (_Float16*)scratch;                                    // 2 MiB (early)
    _Float16* wst  = (_Float16*)(scratch + 2 * 1024 * 1024);                // 2 MiB (early)
    float* Ac = (float*)scratch;                                            // 8 MiB (late, also h0)
    float* Bc = (float*)(scratch + 8 * 1024 * 1024);                        // 8 MiB (late)
    float* wpart = (float*)cand;   // 16 MiB fp32 partials; cand dead until main GEMM

    // 1. casts
    cvt_f32_f16<<<2048, 256, 0, stream>>>(x, xh, M_TOT * K_DIM / 8);
    cvt_f32_f16<<<512, 256, 0, stream>>>(W_in, Wall, D_DIM * K_DIM / 8);
    transpose_cvt<<<dim3(32, 32), dim3(32, 8), 0, stream>>>(W_in + (size_t)D_DIM * K_DIM, wvxT);
    cvt_f32_f16<<<512, 256, 0, stream>>>(W_state, wst, D_DIM * K_DIM / 8);

    // 2. W_comb = W_state @ W_vx -> Wall rows 1024..2047  (split-K x4)
    wcomb_splitk<<<256, 256, 0, stream>>>(wst, wvxT, wpart);
    wcomb_combine<<<1024, 256, 0, stream>>>(wpart, Wall + (size_t)D_DIM * K_DIM);

    // 3. fused projection: [u | cand] = x @ Wall^T  (sigmoid on u half)
    gemm256<<<2048, 256, 0, stream>>>(xh, Wall, uarr, cand);

    // 4. chunked affine scan + fused LN
    scan_pass1<<<(B_DIM * NCH * 128) / 256, 256, 0, stream>>>(uarr, cand, Ac, Bc);
    scan_pass2<<<(B_DIM * D_DIM) / 256, 256, 0, stream>>>(Ac, Bc);
    scan_ln<<<B_DIM * NCH, 64, 0, stream>>>(uarr, cand, Ac, gamma, beta, out);
}

// Round 14
// 296.060 us; speedup vs baseline: 1.1176x; 1.0409x over previous
//
#include <hip/hip_runtime.h>

// ---- problem constants ----
#define D_DIM 1024
#define B_DIM 16
#define T_DIM 2048
#define M_TOT (B_DIM * T_DIM)   // 32768 rows
#define K_DIM 1024
#define LN_EPS 1e-5f
#define CHUNK 16
#define NCH (T_DIM / CHUNK)     // 128 chunks

typedef _Float16 half8 __attribute__((ext_vector_type(8)));
typedef _Float16 half4v __attribute__((ext_vector_type(4)));
typedef float f32x4 __attribute__((ext_vector_type(4)));

// ---------------- merged W-prep: gate cvt | W_state cvt | W_vx transpose ----------------
__global__ __launch_bounds__(256) void prep_w(const float* __restrict__ W_in,
                                              const float* __restrict__ W_state,
                                              _Float16* __restrict__ Wall,     // gate rows 0..1023
                                              _Float16* __restrict__ wvxT,
                                              _Float16* __restrict__ wst) {
    int b = blockIdx.x, tid = threadIdx.x;
    if (b < 512) {                       // W_g -> Wall rows 0..1023 (fp16)
        int i = b * 256 + tid;           // half8 units
        const float4* p = (const float4*)W_in + 2 * (size_t)i;
        float4 a = p[0], c = p[1];
        half8 h;
        h[0] = (_Float16)a.x; h[1] = (_Float16)a.y; h[2] = (_Float16)a.z; h[3] = (_Float16)a.w;
        h[4] = (_Float16)c.x; h[5] = (_Float16)c.y; h[6] = (_Float16)c.z; h[7] = (_Float16)c.w;
        ((half8*)Wall)[i] = h;
    } else if (b < 1024) {               // W_state -> wst (fp16)
        int i = (b - 512) * 256 + tid;
        const float4* p = (const float4*)W_state + 2 * (size_t)i;
        float4 a = p[0], c = p[1];
        half8 h;
        h[0] = (_Float16)a.x; h[1] = (_Float16)a.y; h[2] = (_Float16)a.z; h[3] = (_Float16)a.w;
        h[4] = (_Float16)c.x; h[5] = (_Float16)c.y; h[6] = (_Float16)c.z; h[7] = (_Float16)c.w;
        ((half8*)wst)[i] = h;
    } else {                             // W_vx^T -> wvxT (fp16 transpose, 32x32 tiles)
        __shared__ _Float16 t[32][33];
        int tile = b - 1024;             // 0..1023
        int bx = (tile & 31) * 32, by = (tile >> 5) * 32;
        int tx = tid & 31, ty = tid >> 5; // (32,8)
        const float* src = W_in + (size_t)D_DIM * K_DIM;
#pragma unroll
        for (int j = 0; j < 4; ++j)
            t[ty + 8 * j][tx] = (_Float16)src[(size_t)(by + ty + 8 * j) * 1024 + bx + tx];
        __syncthreads();
#pragma unroll
        for (int j = 0; j < 4; ++j)
            wvxT[(size_t)(bx + ty + 8 * j) * 1024 + by + tx] = t[tx][ty + 8 * j];
    }
}

// ---------------- async global->LDS helper ----------------
__device__ __forceinline__ void gl_lds16(const _Float16* g, _Float16* l) {
    __builtin_amdgcn_global_load_lds(
        (const __attribute__((address_space(1))) unsigned int*)g,
        (__attribute__((address_space(3))) unsigned int*)l,
        16, 0, 0);
}

// ====== 128x256 MFMA GEMM, 4 waves, 2 blocks/CU, x read as FP32 (fused cvt) ======
// A-path: reg-staged fp32->fp16 (LD(t+2) issue early, cvt+ds_write W(t+1) late),
// 2-buffer A LDS. B-path: unchanged proven 3-buffer gl_lds, stage t+2 during t.
// Ledger: per-tile queue {Bglds(t)[4], LD(t+1)[4], Bglds(t+1)[4]} -> vmcnt(4)
// drains Bglds(t)+LD(t+1) exactly; lgkmcnt(0) before end barrier publishes W(t+1).

// Stage 256x32 B-tile (16 KiB, 1024 chunks) = 4 gl_lds / thread.
__device__ __forceinline__ void stageB32(const _Float16* __restrict__ G,
                                         int row0, int kt,
                                         _Float16* lds0, int wid, int lane) {
#pragma unroll
    for (int call = 0; call < 4; ++call) {
        int c0 = call * 256 + wid * 64;
        int c  = c0 + lane;                 // chunk 0..1023
        int rl = c >> 2;                    // row 0..255
        int cc = c & 3;
        int src = cc ^ ((rl >> 1) & 3);     // both-sides swizzle (0 conflicts r7/r13)
        gl_lds16(G + (size_t)(row0 + rl) * 1024 + kt + src * 8,
                 lds0 + (size_t)c0 * 8);
    }
}

// Issue fp32 loads for one 128x32 A-tile (2 chunks/thread = 4 float4).
__device__ __forceinline__ void ldA(const float* __restrict__ X, int m0, int kt,
                                    int wid, int lane,
                                    float4& p0, float4& p1, float4& p2, float4& p3) {
    int c = wid * 64 + lane;               // chunk 0..255 (call 0)
    int rl = c >> 2, cc = c & 3;
    int src = cc ^ ((rl >> 1) & 3);
    const float* g = X + (size_t)(m0 + rl) * 1024 + kt + src * 8;
    p0 = *(const float4*)g;
    p1 = *(const float4*)(g + 4);
    c = 256 + wid * 64 + lane;             // call 1
    rl = c >> 2; cc = c & 3; src = cc ^ ((rl >> 1) & 3);
    g = X + (size_t)(m0 + rl) * 1024 + kt + src * 8;
    p2 = *(const float4*)g;
    p3 = *(const float4*)(g + 4);
}

__device__ __forceinline__ half8 cvt8(const float4& a, const float4& b) {
    half8 h;
    h[0] = (_Float16)a.x; h[1] = (_Float16)a.y; h[2] = (_Float16)a.z; h[3] = (_Float16)a.w;
    h[4] = (_Float16)b.x; h[5] = (_Float16)b.y; h[6] = (_Float16)b.z; h[7] = (_Float16)b.w;
    return h;
}

// cvt + ds_write one A-tile (same layout gl_lds produced: linear chunk order)
__device__ __forceinline__ void wrA(_Float16* lds0, int wid, int lane,
                                    const float4& p0, const float4& p1,
                                    const float4& p2, const float4& p3) {
    *(half8*)(lds0 + (size_t)(wid * 64 + lane) * 8)       = cvt8(p0, p1);
    *(half8*)(lds0 + (size_t)(256 + wid * 64 + lane) * 8) = cvt8(p2, p3);
}

// Fragment read with matching XOR (conflict-free, measured r7/r13).
__device__ __forceinline__ half8 frag32(const _Float16* base, int row, int kq) {
    int cc = kq ^ ((row >> 1) & 3);
    return *(const half8*)(base + (size_t)row * 32 + cc * 8);
}

template <int TA, int TB>
__device__ __forceinline__ void gstep(const float* __restrict__ X,
                                      const _Float16* __restrict__ W,
                                      int m0, int nrow0, int t, int nkt,
                                      int wid, int lane, int wc, int r, int kq,
                                      _Float16 (&As)[2][128][32],
                                      _Float16 (&Bs)[3][256][32],
                                      f32x4 (&acc)[8][4],
                                      float4& l0, float4& l1, float4& l2, float4& l3) {
    half8 rb[4], ra0[4], ra1[4];

    // ---- tile top: drain Bglds(t)+LD(t+1) ; barrier publishes all waves' tile t ----
    if (t + 1 < nkt) asm volatile("s_waitcnt vmcnt(4)" ::: "memory");
    else             asm volatile("s_waitcnt vmcnt(0)" ::: "memory");
    __builtin_amdgcn_s_barrier();
    __builtin_amdgcn_sched_barrier(0);       // pin reads below barrier (rule #18)

    // ---- ds reads of tile t frags ----
#pragma unroll
    for (int ni = 0; ni < 4; ni++) rb[ni]  = frag32(&Bs[TB][0][0], wc * 64 + ni * 16 + r, kq);
#pragma unroll
    for (int mi = 0; mi < 4; mi++) ra0[mi] = frag32(&As[TA][0][0], mi * 16 + r, kq);

    // ---- W(t+1): cvt landed LD(t+1) regs -> As[TA^1] ----
    if (t + 1 < nkt) wrA(&As[TA ^ 1][0][0], wid, lane, l0, l1, l2, l3);
    // ---- LD(t+2): issue next fp32 A loads (overwrites l0..l3, WAR in-order) ----
    if (t + 2 < nkt) ldA(X, m0, (t + 2) << 5, wid, lane, l0, l1, l2, l3);
    // ---- Bglds(t+2) ----
    if (t + 2 < nkt) stageB32(W, nrow0, (t + 2) << 5, &Bs[(TB + 2) % 3][0][0], wid, lane);

    __builtin_amdgcn_s_setprio(1);
#pragma unroll
    for (int mi = 0; mi < 4; mi++)
#pragma unroll
        for (int ni = 0; ni < 4; ni++)
            acc[mi][ni] = __builtin_amdgcn_mfma_f32_16x16x32_f16(ra0[mi], rb[ni], acc[mi][ni], 0, 0, 0);
    __builtin_amdgcn_s_setprio(0);

#pragma unroll
    for (int mi = 0; mi < 4; mi++) ra1[mi] = frag32(&As[TA][0][0], 64 + mi * 16 + r, kq);
    __builtin_amdgcn_s_setprio(1);
#pragma unroll
    for (int mi = 0; mi < 4; mi++)
#pragma unroll
        for (int ni = 0; ni < 4; ni++)
            acc[4 + mi][ni] = __builtin_amdgcn_mfma_f32_16x16x32_f16(ra1[mi], rb[ni], acc[4 + mi][ni], 0, 0, 0);
    __builtin_amdgcn_s_setprio(0);
    asm volatile("s_waitcnt lgkmcnt(0)" ::: "memory");   // publish W(t+1) before barrier
    __builtin_amdgcn_s_barrier();
}

// W rows 0..1023 = gate weights, 1024..2047 = W_comb. nt<4 -> sigmoid -> out0.
__global__ __launch_bounds__(256, 2) void gemm256(const float* __restrict__ X,
                                                  const _Float16* __restrict__ W,
                                                  _Float16* __restrict__ out0,
                                                  _Float16* __restrict__ out1) {
    __shared__ _Float16 As[2][128][32];   // 16 KiB
    __shared__ _Float16 Bs[3][256][32];   // 48 KiB  (64 KiB total -> 2 blocks/CU)

    int bid = blockIdx.x;                 // 2048 blocks
    int xcd = bid & 7, lin = bid >> 3;    // 256 blocks/XCD
    int mt = xcd * 32 + (lin >> 3);       // 32 mt x 8 nt per XCD
    int nt = lin & 7;
    int m0 = mt * 128, nrow0 = nt * 256;

    int tid = threadIdx.x, wid = tid >> 6, lane = tid & 63;
    int wc = wid;                          // 1x4 wave grid: wave owns 64 cols
    int r = lane & 15, kq = lane >> 4;

    f32x4 acc[8][4];
#pragma unroll
    for (int i = 0; i < 8; i++)
#pragma unroll
        for (int j = 0; j < 4; j++) acc[i][j] = (f32x4)0.f;

    const int nkt = K_DIM >> 5;            // 32 K-tiles
    float4 l0, l1, l2, l3;

    // ---- prologue: LD(0) ; drain ; W(0) ; Bglds(0) ; LD(1) ; Bglds(1) ; publish ----
    ldA(X, m0, 0, wid, lane, l0, l1, l2, l3);
    asm volatile("s_waitcnt vmcnt(0)" ::: "memory");
    wrA(&As[0][0][0], wid, lane, l0, l1, l2, l3);
    stageB32(W, nrow0, 0,  &Bs[0][0][0], wid, lane);
    ldA(X, m0, 32, wid, lane, l0, l1, l2, l3);
    stageB32(W, nrow0, 32, &Bs[1][0][0], wid, lane);
    asm volatile("s_waitcnt lgkmcnt(0)" ::: "memory");   // W(0) writes done pre-barrier
    // entering loop: queue = {Bglds(0)[4], LD(1)[4], Bglds(1)[4]} -> t=0 vmcnt(4) ok

    for (int t0 = 0; t0 < nkt; t0 += 6) {
        gstep<0, 0>(X, W, m0, nrow0, t0,     nkt, wid, lane, wc, r, kq, As, Bs, acc, l0, l1, l2, l3);
        if (t0 + 1 < nkt) gstep<1, 1>(X, W, m0, nrow0, t0 + 1, nkt, wid, lane, wc, r, kq, As, Bs, acc, l0, l1, l2, l3);
        if (t0 + 2 < nkt) gstep<0, 2>(X, W, m0, nrow0, t0 + 2, nkt, wid, lane, wc, r, kq, As, Bs, acc, l0, l1, l2, l3);
        if (t0 + 3 < nkt) gstep<1, 0>(X, W, m0, nrow0, t0 + 3, nkt, wid, lane, wc, r, kq, As, Bs, acc, l0, l1, l2, l3);
        if (t0 + 4 < nkt) gstep<0, 1>(X, W, m0, nrow0, t0 + 4, nkt, wid, lane, wc, r, kq, As, Bs, acc, l0, l1, l2, l3);
        if (t0 + 5 < nkt) gstep<1, 2>(X, W, m0, nrow0, t0 + 5, nkt, wid, lane, wc, r, kq, As, Bs, acc, l0, l1, l2, l3);
    }

    // ---- epilogue: C/D layout col = lane&15, row = (lane>>4)*4 + q ----
    bool isGate = (nt < 4);
    _Float16* dst = isGate ? out0 : out1;
    int cb = (nt & 3) * 256 + wc * 64;
    int rr = kq * 4;
#pragma unroll
    for (int mi = 0; mi < 8; mi++) {
        int mbase = m0 + mi * 16 + rr;
#pragma unroll
        for (int ni = 0; ni < 4; ni++) {
            int n = cb + ni * 16 + r;
#pragma unroll
            for (int q = 0; q < 4; q++) {
                float v = acc[mi][ni][q];
                if (isGate) v = 1.f / (1.f + __expf(-v));
                dst[(size_t)(mbase + q) * D_DIM + n] = (_Float16)v;
            }
        }
    }
}

// ========== split-K W_comb GEMM (128x128 tile, r2-validated structure) ==========
__global__ __launch_bounds__(256) void wcomb_splitk(const _Float16* __restrict__ A,
                                                    const _Float16* __restrict__ Bm,
                                                    float* __restrict__ part) {
    __shared__ _Float16 As[128 * 32];
    __shared__ _Float16 Bs[128 * 32];
    int bid = blockIdx.x;                 // mt + 8*nt + 64*slice
    int mt = bid & 7, nt = (bid >> 3) & 7, sl = bid >> 6;
    int m0 = mt * 128, n0 = nt * 128, kbeg = sl * 256;
    int tid = threadIdx.x, wid = tid >> 6, lane = tid & 63;
    int wr = wid >> 1, wc = wid & 1;

    f32x4 acc[4][4];
#pragma unroll
    for (int i = 0; i < 4; i++)
#pragma unroll
        for (int j = 0; j < 4; j++) acc[i][j] = (f32x4)0.f;

    int r = lane & 15, kq = lane >> 4;

    for (int kt = kbeg; kt < kbeg + 256; kt += 32) {
        __syncthreads();
#pragma unroll
        for (int j = 0; j < 2; ++j) {
            int f = j * 256 + tid;
            int row = f >> 2, kc = f & 3;
            gl_lds16(A + (size_t)(m0 + row) * 1024 + kt + kc * 8, As + (size_t)(j * 256 + wid * 64) * 8);
            gl_lds16(Bm + (size_t)(n0 + row) * 1024 + kt + kc * 8, Bs + (size_t)(j * 256 + wid * 64) * 8);
        }
        __syncthreads();
        half8 af[4], bf[4];
#pragma unroll
        for (int mi = 0; mi < 4; mi++) af[mi] = *(const half8*)&As[(wr * 64 + mi * 16 + r) * 32 + kq * 8];
#pragma unroll
        for (int ni = 0; ni < 4; ni++) bf[ni] = *(const half8*)&Bs[(wc * 64 + ni * 16 + r) * 32 + kq * 8];
#pragma unroll
        for (int mi = 0; mi < 4; mi++)
#pragma unroll
            for (int ni = 0; ni < 4; ni++)
                acc[mi][ni] = __builtin_amdgcn_mfma_f32_16x16x32_f16(af[mi], bf[ni], acc[mi][ni], 0, 0, 0);
    }

    int rr = kq * 4;
    float* pbp = part + (size_t)sl * 1048576;
#pragma unroll
    for (int mi = 0; mi < 4; mi++) {
        int mbase = m0 + wr * 64 + mi * 16 + rr;
#pragma unroll
        for (int ni = 0; ni < 4; ni++) {
            int n = n0 + wc * 64 + ni * 16 + r;
#pragma unroll
            for (int q = 0; q < 4; q++)
                pbp[(size_t)(mbase + q) * 1024 + n] = acc[mi][ni][q];
        }
    }
}

// combine 4 split-K slices -> W rows 1024..2047 (row-major fp16)
__global__ __launch_bounds__(256) void wcomb_combine(const float* __restrict__ part,
                                                     _Float16* __restrict__ out) {
    int i = blockIdx.x * 256 + threadIdx.x;   // 0..262143 (float4 units)
    float4 s0 = ((const float4*)part)[i];
    float4 s1 = ((const float4*)(part + 1048576))[i];
    float4 s2 = ((const float4*)(part + 2097152))[i];
    float4 s3 = ((const float4*)(part + 3145728))[i];
    half4v o;
    o[0] = (_Float16)(s0.x + s1.x + s2.x + s3.x);
    o[1] = (_Float16)(s0.y + s1.y + s2.y + s3.y);
    o[2] = (_Float16)(s0.z + s1.z + s2.z + s3.z);
    o[3] = (_Float16)(s0.w + s1.w + s2.w + s3.w);
    ((half4v*)out)[i] = o;
}

// ---------------- chunked affine scan, pass 1 (CHUNK=16) ----------------
__global__ __launch_bounds__(256) void scan_pass1(const _Float16* __restrict__ u,
                                                  const _Float16* __restrict__ cd,
                                                  float* __restrict__ Ac, float* __restrict__ Bc) {
    int idx = blockIdx.x * 256 + threadIdx.x;   // (b*NCH + ch)*128 + dg
    int dg = idx & 127, bc = idx >> 7;
    int b = bc >> 7, ch = bc & (NCH - 1);
    int d0 = dg * 8;
    size_t base = ((size_t)b * T_DIM + (size_t)ch * CHUNK) * D_DIM + d0;
    float Aa[8], Bb[8];
#pragma unroll
    for (int j = 0; j < 8; ++j) { Aa[j] = 1.f; Bb[j] = 0.f; }
#pragma unroll
    for (int t = 0; t < CHUNK; ++t) {
        half8 u8 = *(const half8*)&u[base + (size_t)t * D_DIM];
        half8 c8 = *(const half8*)&cd[base + (size_t)t * D_DIM];
#pragma unroll
        for (int j = 0; j < 8; ++j) {
            float ut = (float)u8[j], ct = (float)c8[j];
            Aa[j] *= ut;
            Bb[j] = fmaf(ut, Bb[j], (1.f - ut) * ct);
        }
    }
    size_t o = (size_t)bc * D_DIM + d0;
    *(float4*)&Ac[o]     = *(float4*)&Aa[0];
    *(float4*)&Ac[o + 4] = *(float4*)&Aa[4];
    *(float4*)&Bc[o]     = *(float4*)&Bb[0];
    *(float4*)&Bc[o + 4] = *(float4*)&Bb[4];
}

// pass 2: sequential over chunks; AcH0 doubles as h0 output (read-before-write)
__global__ __launch_bounds__(256) void scan_pass2(float* __restrict__ AcH0,
                                                  const float* __restrict__ Bc) {
    int idx = blockIdx.x * 256 + threadIdx.x;   // b*D + d, 16384 total
    int b = idx >> 10, d = idx & (D_DIM - 1);
    float h = 0.f;
#pragma unroll 8
    for (int ch = 0; ch < NCH; ++ch) {
        size_t k = ((size_t)(b * NCH + ch) << 10) + d;
        float a = AcH0[k];
        float bv = Bc[k];
        AcH0[k] = h;
        h = fmaf(a, h, bv);
    }
}

// ---------------- fused scan pass 3 + LayerNorm (1 wave, 16 dims/lane) ----------------
__global__ __launch_bounds__(64) void scan_ln(const _Float16* __restrict__ u,
                                              const _Float16* __restrict__ cd,
                                              const float* __restrict__ h0,
                                              const float* __restrict__ gamma,
                                              const float* __restrict__ beta,
                                              float* __restrict__ outp) {
    int bc = blockIdx.x;                // b*NCH + ch
    int b = bc >> 7, ch = bc & (NCH - 1);
    int lane = threadIdx.x;             // 0..63
    int d0 = lane * 16;
    size_t base = ((size_t)b * T_DIM + (size_t)ch * CHUNK) * D_DIM + d0;

    float g[16], be[16], h[16];
#pragma unroll
    for (int j = 0; j < 16; j += 4) {
        *(float4*)&g[j]  = *(const float4*)&gamma[d0 + j];
        *(float4*)&be[j] = *(const float4*)&beta[d0 + j];
    }
    size_t o = (size_t)bc * D_DIM + d0;
#pragma unroll
    for (int j = 0; j < 16; j += 4) *(float4*)&h[j] = *(const float4*)&h0[o + j];

    for (int t = 0; t < CHUNK; ++t) {
        size_t row = base + (size_t)t * D_DIM;
        half8 ua = *(const half8*)&u[row];
        half8 ub = *(const half8*)&u[row + 8];
        half8 ca = *(const half8*)&cd[row];
        half8 cb = *(const half8*)&cd[row + 8];
        float s = 0.f, q = 0.f;
#pragma unroll
        for (int j = 0; j < 8; ++j) {
            float ut = (float)ua[j], ct = (float)ca[j];
            h[j] = fmaf(ut, h[j] - ct, ct);
            s += h[j]; q += h[j] * h[j];
        }
#pragma unroll
        for (int j = 0; j < 8; ++j) {
            float ut = (float)ub[j], ct = (float)cb[j];
            h[8 + j] = fmaf(ut, h[8 + j] - ct, ct);
            s += h[8 + j]; q += h[8 + j] * h[8 + j];
        }
#pragma unroll
        for (int off = 32; off > 0; off >>= 1) {
            s += __shfl_xor(s, off);
            q += __shfl_xor(q, off);
        }
        float mu = s * (1.f / D_DIM);
        float var = q * (1.f / D_DIM) - mu * mu;
        float rs = rsqrtf(var + LN_EPS);
        float o16[16];
#pragma unroll
        for (int j = 0; j < 16; ++j) o16[j] = (h[j] - mu) * rs * g[j] + be[j];
#pragma unroll
        for (int j = 0; j < 16; j += 4) *(float4*)&outp[row + j] = *(float4*)&o16[j];
    }
}

extern "C" void kernel_launch(void* const* d_in, const int* in_sizes, int n_in,
                              void* d_out, int out_size, void* d_ws, size_t ws_size,
                              hipStream_t stream) {
    const float* x       = (const float*)d_in[0];
    const float* W_in    = (const float*)d_in[1];
    const float* W_state = (const float*)d_in[2];
    const float* gamma   = (const float*)d_in[3];
    const float* beta    = (const float*)d_in[4];
    float* out = (float*)d_out;

    char* w = (char*)d_ws;
    size_t off = 0;
    auto carve = [&](size_t bytes) {
        void* p = w + off;
        off += (bytes + 255) & ~(size_t)255;
        return p;
    };
    _Float16* Wall = (_Float16*)carve((size_t)2 * D_DIM * K_DIM * 2);       // 4 MiB (W_g ; W_comb)
    _Float16* uarr = (_Float16*)carve((size_t)M_TOT * D_DIM * 2);           // 64 MiB
    _Float16* cand = (_Float16*)carve((size_t)M_TOT * D_DIM * 2);           // 64 MiB
    char* scratch  = (char*)carve((size_t)16 * 1024 * 1024);                // 16 MiB shared region
    _Float16* wvxT = (_Float16*)scratch;                                    // 2 MiB (early)
    _Float16* wst  = (_Float16*)(scratch + 2 * 1024 * 1024);                // 2 MiB (early)
    float* Ac = (float*)scratch;                                            // 8 MiB (late, also h0)
    float* Bc = (float*)(scratch + 8 * 1024 * 1024);                        // 8 MiB (late)
    float* wpart = (float*)cand;   // 16 MiB fp32 partials; cand dead until main GEMM

    // 1. merged W-prep (gate cvt | W_state cvt | W_vx transpose)
    prep_w<<<2048, 256, 0, stream>>>(W_in, W_state, Wall, wvxT, wst);

    // 2. W_comb = W_state @ W_vx -> Wall rows 1024..2047  (split-K x4)
    wcomb_splitk<<<256, 256, 0, stream>>>(wst, wvxT, wpart);
    wcomb_combine<<<1024, 256, 0, stream>>>(wpart, Wall + (size_t)D_DIM * K_DIM);

    // 3. fused projection: [u | cand] = x @ Wall^T  (x read fp32, cvt fused into staging)
    gemm256<<<2048, 256, 0, stream>>>(x, Wall, uarr, cand);

    // 4. chunked affine scan + fused LN
    scan_pass1<<<(B_DIM * NCH * 128) / 256, 256, 0, stream>>>(uarr, cand, Ac, Bc);
    scan_pass2<<<(B_DIM * D_DIM) / 256, 256, 0, stream>>>(Ac, Bc);
    scan_ln<<<B_DIM * NCH, 64, 0, stream>>>(uarr, cand, Ac, gamma, beta, out);
}